// Round 2
// baseline (259.614 us; speedup 1.0000x reference)
//
#include <hip/hip_runtime.h>
#include <hip/hip_bf16.h>

#define S_ 2048
#define D_ 64
#define BM 64           // q rows per block (4 waves x 16)
#define BN 64           // key tile
#define LDSTR 72        // padded LDS row stride (elements): 144B rows keep 16B align, 2-way banks

typedef __attribute__((ext_vector_type(8))) short bf16x8;   // 8 bf16 = 4 VGPRs (MFMA A/B frag)
typedef __attribute__((ext_vector_type(4))) float f32x4;    // MFMA C/D frag

__device__ __forceinline__ unsigned short f2bf(float f) {
    union { float f; unsigned int i; } x; x.f = f;
    unsigned int i = x.i;
    return (unsigned short)((i + 0x7fffu + ((i >> 16) & 1u)) >> 16);   // RNE
}

__device__ __forceinline__ f32x4 vmax4(f32x4 a, f32x4 b) {
    f32x4 r;
#pragma unroll
    for (int j = 0; j < 4; ++j) r[j] = fmaxf(a[j], b[j]);
    return r;
}

__device__ __forceinline__ f32x4 shfl_xor4(f32x4 x, int m) {
    f32x4 r;
#pragma unroll
    for (int j = 0; j < 4; ++j) r[j] = __shfl_xor(x[j], m, 64);
    return r;
}

// Flash attention fwd. q,k,v: fp32 [32][2048][64]; out: fp32 same shape.
// Internally: bf16 MFMA (16x16x32), fp32 accumulate, online softmax in log2 domain.
__global__ __launch_bounds__(256, 2) void fattn(const float* __restrict__ q,
                                                const float* __restrict__ k,
                                                const float* __restrict__ v,
                                                float* __restrict__ out) {
    __shared__ ushort Kt[BN * LDSTR];        // [key][d]   bf16
    __shared__ ushort Vt[D_ * LDSTR];        // [d][key]   bf16 (transposed)
    __shared__ ushort Pb[4 * 16 * LDSTR];    // per-wave P round-trip [row][key]

    const int tid  = threadIdx.x;
    const int wid  = tid >> 6;
    const int lane = tid & 63;
    const int ln   = lane & 15;      // MFMA n/m lane index
    const int quad = lane >> 4;      // MFMA k-group / row-group

    const int batch = blockIdx.x >> 5;       // 32 q-tiles per batch
    const int qtile = blockIdx.x & 31;
    const int qbase = qtile * BM;

    const float* qp = q + (size_t)batch * S_ * D_;
    const float* kp = k + (size_t)batch * S_ * D_;
    const float* vp = v + (size_t)batch * S_ * D_;

    // ---- persistent Q A-frags: A[m=ln][k=quad*8+j (+32 for second frag)] ----
    const int qr0 = qbase + wid * 16;
    bf16x8 qf0, qf1;
    {
        const float* qrow = qp + (size_t)(qr0 + ln) * D_ + quad * 8;
        union { bf16x8 v; ushort u[8]; } u0, u1;
#pragma unroll
        for (int j = 0; j < 8; ++j) {
            u0.u[j] = f2bf(qrow[j]);
            u1.u[j] = f2bf(qrow[j + 32]);
        }
        qf0 = u0.v; qf1 = u1.v;
    }

    f32x4 O[4];                      // out accum, C-layout: col=ot*16+ln, row=quad*4+reg
    const f32x4 zero4 = {0.f, 0.f, 0.f, 0.f};
#pragma unroll
    for (int ot = 0; ot < 4; ++ot) O[ot] = zero4;
    f32x4 mrow = {-INFINITY, -INFINITY, -INFINITY, -INFINITY};
    f32x4 lrow = zero4;

    ushort* pw = Pb + wid * 16 * LDSTR;      // wave-private P buffer
    const int fragcol = quad * 8;
    const float SC = 0.18033688011112042f;   // log2(e)/sqrt(64)

    for (int kt = 0; kt < S_; kt += BN) {
        __syncthreads();             // protect LDS reuse vs previous iter's reads
        // ---- stage K [key][d] and V^T [d][key], fp32 -> bf16 ----
        {
            int idx = tid;
#pragma unroll
            for (int p = 0; p < 4; ++p, idx += 256) {
                const int key = idx >> 4;        // 0..63
                const int c   = idx & 15;        // float4 chunk along d
                const size_t goff = (size_t)(kt + key) * D_ + c * 4;
                const float4 k4 = *(const float4*)(kp + goff);
                ushort* kd = &Kt[key * LDSTR + c * 4];
                kd[0] = f2bf(k4.x); kd[1] = f2bf(k4.y);
                kd[2] = f2bf(k4.z); kd[3] = f2bf(k4.w);
                const float4 v4 = *(const float4*)(vp + goff);
                Vt[(c * 4 + 0) * LDSTR + key] = f2bf(v4.x);
                Vt[(c * 4 + 1) * LDSTR + key] = f2bf(v4.y);
                Vt[(c * 4 + 2) * LDSTR + key] = f2bf(v4.z);
                Vt[(c * 4 + 3) * LDSTR + key] = f2bf(v4.w);
            }
        }
        __syncthreads();

        // ---- S = (Q K^T) * scale : 4 col-tiles of 16 keys ----
        f32x4 sa[4];
#pragma unroll
        for (int nt = 0; nt < 4; ++nt) {
            const ushort* kr = &Kt[(nt * 16 + ln) * LDSTR + fragcol];
            bf16x8 k0 = *(const bf16x8*)(kr);
            bf16x8 k1 = *(const bf16x8*)(kr + 32);
            f32x4 acc = __builtin_amdgcn_mfma_f32_16x16x32_bf16(qf0, k0, zero4, 0, 0, 0);
            sa[nt]    = __builtin_amdgcn_mfma_f32_16x16x32_bf16(qf1, k1, acc, 0, 0, 0);
        }
#pragma unroll
        for (int nt = 0; nt < 4; ++nt) sa[nt] *= SC;   // logits in log2 domain

        // ---- online softmax (rows in regs; 64 keys = 4 nt x 16 lanes-of-same-quad) ----
        f32x4 tmax = vmax4(vmax4(sa[0], sa[1]), vmax4(sa[2], sa[3]));
#pragma unroll
        for (int m = 1; m < 16; m <<= 1) tmax = vmax4(tmax, shfl_xor4(tmax, m));
        const f32x4 mnew = vmax4(mrow, tmax);
        f32x4 alpha;
#pragma unroll
        for (int j = 0; j < 4; ++j) alpha[j] = exp2f(mrow[j] - mnew[j]);
#pragma unroll
        for (int nt = 0; nt < 4; ++nt)
#pragma unroll
            for (int j = 0; j < 4; ++j) sa[nt][j] = exp2f(sa[nt][j] - mnew[j]);
        f32x4 rs = sa[0] + sa[1] + sa[2] + sa[3];
#pragma unroll
        for (int m = 1; m < 16; m <<= 1) rs += shfl_xor4(rs, m);
        lrow = lrow * alpha + rs;
        mrow = mnew;
#pragma unroll
        for (int ot = 0; ot < 4; ++ot) O[ot] *= alpha;

        // ---- P: C-layout -> A-layout via wave-private LDS round trip ----
#pragma unroll
        for (int nt = 0; nt < 4; ++nt)
#pragma unroll
            for (int r = 0; r < 4; ++r)
                pw[(quad * 4 + r) * LDSTR + nt * 16 + ln] = f2bf(sa[nt][r]);
        __threadfence_block();       // order write->read; DS ops are in-order per wave

        const ushort* pr = pw + ln * LDSTR + fragcol;
        bf16x8 pa0 = *(const bf16x8*)(pr);
        bf16x8 pa1 = *(const bf16x8*)(pr + 32);

        // ---- O += P V ----
#pragma unroll
        for (int ot = 0; ot < 4; ++ot) {
            const ushort* vr = &Vt[(ot * 16 + ln) * LDSTR + fragcol];
            bf16x8 v0 = *(const bf16x8*)(vr);
            bf16x8 v1 = *(const bf16x8*)(vr + 32);
            O[ot] = __builtin_amdgcn_mfma_f32_16x16x32_bf16(pa0, v0, O[ot], 0, 0, 0);
            O[ot] = __builtin_amdgcn_mfma_f32_16x16x32_bf16(pa1, v1, O[ot], 0, 0, 0);
        }
    }

    // ---- epilogue: normalize, direct fp32 stores from C-layout ----
    // element (row=quad*4+r, col=ot*16+ln); per instr each quad writes a
    // contiguous 64B segment -> 4x64B per wave-store, adequately coalesced.
    f32x4 linv;
#pragma unroll
    for (int j = 0; j < 4; ++j) linv[j] = 1.0f / lrow[j];
    float* op = out + (size_t)batch * S_ * D_;
#pragma unroll
    for (int r = 0; r < 4; ++r) {
        float* orow = op + (size_t)(qr0 + quad * 4 + r) * D_ + ln;
#pragma unroll
        for (int ot = 0; ot < 4; ++ot)
            orow[ot * 16] = O[ot][r] * linv[r];
    }
}

extern "C" void kernel_launch(void* const* d_in, const int* in_sizes, int n_in,
                              void* d_out, int out_size, void* d_ws, size_t ws_size,
                              hipStream_t stream) {
    const float* q = (const float*)d_in[0];
    const float* k = (const float*)d_in[1];
    const float* v = (const float*)d_in[2];
    float* o = (float*)d_out;
    // 32 batches * (2048/64) q-tiles = 1024 blocks, 256 threads (4 waves)
    fattn<<<dim3(1024), dim3(256), 0, stream>>>(q, k, v, o);
}

// Round 3
// 219.137 us; speedup vs baseline: 1.1847x; 1.1847x over previous
//
#include <hip/hip_runtime.h>
#include <hip/hip_bf16.h>

#define S_ 2048
#define D_ 64
#define BM 64           // q rows per block (4 waves x 16)
#define BN 64           // key tile
#define LDSTR 72        // padded LDS row stride (elems): 144B rows, 16B-aligned, dword stride 36

typedef __attribute__((ext_vector_type(8))) short bf16x8;   // 8 bf16 = 4 VGPRs (MFMA A/B frag)
typedef __attribute__((ext_vector_type(4))) float f32x4;    // MFMA C/D frag

__device__ __forceinline__ unsigned short f2bf(float f) {
    union { float f; unsigned int i; } x; x.f = f;
    unsigned int i = x.i;
    return (unsigned short)((i + 0x7fffu + ((i >> 16) & 1u)) >> 16);   // RNE
}

__device__ __forceinline__ f32x4 vmax4(f32x4 a, f32x4 b) {
    f32x4 r;
#pragma unroll
    for (int j = 0; j < 4; ++j) r[j] = fmaxf(a[j], b[j]);
    return r;
}

__device__ __forceinline__ f32x4 shfl_xor4(f32x4 x, int m) {
    f32x4 r;
#pragma unroll
    for (int j = 0; j < 4; ++j) r[j] = __shfl_xor(x[j], m, 64);
    return r;
}

// ---- prep A: K fp32 -> bf16, same [b][s][d] layout. 8 elems/thread. ----
__global__ __launch_bounds__(256) void prep_cvt(const float* __restrict__ src,
                                                ushort* __restrict__ dst) {
    const size_t base = ((size_t)blockIdx.x * 256 + threadIdx.x) * 8;
    const float4 a = *(const float4*)(src + base);
    const float4 b = *(const float4*)(src + base + 4);
    union { ushort u[8]; uint4 v; } o;
    o.u[0] = f2bf(a.x); o.u[1] = f2bf(a.y); o.u[2] = f2bf(a.z); o.u[3] = f2bf(a.w);
    o.u[4] = f2bf(b.x); o.u[5] = f2bf(b.y); o.u[6] = f2bf(b.z); o.u[7] = f2bf(b.w);
    *(uint4*)(dst + base) = o.v;
}

// ---- prep B: V fp32 [b][s][d] -> bf16 V^T [b][d][s], 64x64 tiles via LDS ----
__global__ __launch_bounds__(256) void prep_vt(const float* __restrict__ v,
                                               ushort* __restrict__ vt) {
    __shared__ float Lf[64 * 68];    // fp32 tile, pad 68 keeps float4 16B-aligned
    const int batch = blockIdx.x >> 5;
    const int kt    = (blockIdx.x & 31) * 64;
    const float* vb = v + (size_t)batch * S_ * D_ + (size_t)kt * D_;
    const int t = threadIdx.x;
#pragma unroll
    for (int p = 0; p < 4; ++p) {
        const int c   = p * 256 + t;     // float4 chunk 0..1023
        const int key = c >> 4;
        const int dp  = c & 15;
        const float4 f = *(const float4*)(vb + key * 64 + dp * 4);
        *(float4*)(&Lf[key * 68 + dp * 4]) = f;
    }
    __syncthreads();
    const int d  = t >> 2;       // 0..63
    const int kb = t & 3;        // 16-key group
    union { ushort u[8]; uint4 vv; } o0, o1;
#pragma unroll
    for (int j = 0; j < 8; ++j) {
        o0.u[j] = f2bf(Lf[(kb * 16 + j) * 68 + d]);
        o1.u[j] = f2bf(Lf[(kb * 16 + 8 + j) * 68 + d]);
    }
    ushort* ob = vt + (size_t)batch * D_ * S_ + (size_t)d * S_ + kt + kb * 16;
    *(uint4*)(ob)     = o0.vv;
    *(uint4*)(ob + 8) = o1.vv;
}

// ---- flash attention: q fp32; K bf16 [b][s][d]; V^T bf16 [b][d][s]; out fp32 ----
__global__ __launch_bounds__(256, 2) void fattn(const float* __restrict__ q,
                                                const ushort* __restrict__ kbf,
                                                const ushort* __restrict__ vtb_g,
                                                float* __restrict__ out) {
    __shared__ ushort Kt[BN * LDSTR];        // [key][d]   bf16
    __shared__ ushort Vt[D_ * LDSTR];        // [d][key]   bf16
    __shared__ ushort Pb[4 * 16 * LDSTR];    // per-wave P round-trip [row][key]

    const int tid  = threadIdx.x;
    const int wid  = tid >> 6;
    const int lane = tid & 63;
    const int ln   = lane & 15;
    const int quad = lane >> 4;

    const int batch = blockIdx.x >> 5;
    const int qtile = blockIdx.x & 31;
    const int qbase = qtile * BM;

    const float*  qp  = q     + (size_t)batch * S_ * D_;
    const ushort* kp  = kbf   + (size_t)batch * S_ * D_;
    const ushort* vtb = vtb_g + (size_t)batch * D_ * S_;

    // ---- persistent Q A-frags ----
    const int qr0 = qbase + wid * 16;
    bf16x8 qf0, qf1;
    {
        const float* qrow = qp + (size_t)(qr0 + ln) * D_ + quad * 8;
        union { bf16x8 v; ushort u[8]; } u0, u1;
#pragma unroll
        for (int j = 0; j < 8; ++j) {
            u0.u[j] = f2bf(qrow[j]);
            u1.u[j] = f2bf(qrow[j + 32]);
        }
        qf0 = u0.v; qf1 = u1.v;
    }

    f32x4 O[4];
    const f32x4 zero4 = {0.f, 0.f, 0.f, 0.f};
#pragma unroll
    for (int ot = 0; ot < 4; ++ot) O[ot] = zero4;
    f32x4 mrow = {-INFINITY, -INFINITY, -INFINITY, -INFINITY};
    f32x4 lrow = zero4;

    ushort* pw = Pb + wid * 16 * LDSTR;
    const int fragcol = quad * 8;
    const float SC = 0.18033688011112042f;   // log2(e)/sqrt(64)

    for (int kt = 0; kt < S_; kt += BN) {
        __syncthreads();
        // ---- stage K tile (contiguous 8KB) and V^T tile, pure uint4 copies ----
        {
            const ushort* ktile = kp + (size_t)kt * D_;
#pragma unroll
            for (int p = 0; p < 2; ++p) {
                const int c    = p * 256 + tid;   // 16B chunk 0..511
                const int row  = c >> 3;          // key for K, d for V^T
                const int part = c & 7;
                *(uint4*)(&Kt[row * LDSTR + part * 8]) =
                    *(const uint4*)(ktile + c * 8);
                *(uint4*)(&Vt[row * LDSTR + part * 8]) =
                    *(const uint4*)(vtb + (size_t)row * S_ + kt + part * 8);
            }
        }
        __syncthreads();

        // ---- S = (Q K^T) * scale ----
        f32x4 sa[4];
#pragma unroll
        for (int nt = 0; nt < 4; ++nt) {
            const ushort* kr = &Kt[(nt * 16 + ln) * LDSTR + fragcol];
            bf16x8 k0 = *(const bf16x8*)(kr);
            bf16x8 k1 = *(const bf16x8*)(kr + 32);
            f32x4 acc = __builtin_amdgcn_mfma_f32_16x16x32_bf16(qf0, k0, zero4, 0, 0, 0);
            sa[nt]    = __builtin_amdgcn_mfma_f32_16x16x32_bf16(qf1, k1, acc, 0, 0, 0);
        }
#pragma unroll
        for (int nt = 0; nt < 4; ++nt) sa[nt] *= SC;   // log2-domain logits

        // ---- online softmax ----
        f32x4 tmax = vmax4(vmax4(sa[0], sa[1]), vmax4(sa[2], sa[3]));
#pragma unroll
        for (int m = 1; m < 16; m <<= 1) tmax = vmax4(tmax, shfl_xor4(tmax, m));
        const f32x4 mnew = vmax4(mrow, tmax);
        f32x4 alpha;
#pragma unroll
        for (int j = 0; j < 4; ++j) alpha[j] = exp2f(mrow[j] - mnew[j]);
#pragma unroll
        for (int nt = 0; nt < 4; ++nt)
#pragma unroll
            for (int j = 0; j < 4; ++j) sa[nt][j] = exp2f(sa[nt][j] - mnew[j]);
        f32x4 rs = sa[0] + sa[1] + sa[2] + sa[3];
#pragma unroll
        for (int m = 1; m < 16; m <<= 1) rs += shfl_xor4(rs, m);
        lrow = lrow * alpha + rs;
        mrow = mnew;
#pragma unroll
        for (int ot = 0; ot < 4; ++ot) O[ot] *= alpha;

        // ---- P: C-layout -> A-layout via wave-private LDS round trip ----
#pragma unroll
        for (int nt = 0; nt < 4; ++nt)
#pragma unroll
            for (int r = 0; r < 4; ++r)
                pw[(quad * 4 + r) * LDSTR + nt * 16 + ln] = f2bf(sa[nt][r]);
        __threadfence_block();

        const ushort* pr = pw + ln * LDSTR + fragcol;
        bf16x8 pa0 = *(const bf16x8*)(pr);
        bf16x8 pa1 = *(const bf16x8*)(pr + 32);

        // ---- O += P V ----
#pragma unroll
        for (int ot = 0; ot < 4; ++ot) {
            const ushort* vr = &Vt[(ot * 16 + ln) * LDSTR + fragcol];
            bf16x8 v0 = *(const bf16x8*)(vr);
            bf16x8 v1 = *(const bf16x8*)(vr + 32);
            O[ot] = __builtin_amdgcn_mfma_f32_16x16x32_bf16(pa0, v0, O[ot], 0, 0, 0);
            O[ot] = __builtin_amdgcn_mfma_f32_16x16x32_bf16(pa1, v1, O[ot], 0, 0, 0);
        }
    }

    // ---- epilogue: normalize, fp32 stores from C-layout (64B/quad segments) ----
    f32x4 linv;
#pragma unroll
    for (int j = 0; j < 4; ++j) linv[j] = 1.0f / lrow[j];
    float* op = out + (size_t)batch * S_ * D_;
#pragma unroll
    for (int r = 0; r < 4; ++r) {
        float* orow = op + (size_t)(qr0 + quad * 4 + r) * D_ + ln;
#pragma unroll
        for (int ot = 0; ot < 4; ++ot)
            orow[ot * 16] = O[ot][r] * linv[r];
    }
}

extern "C" void kernel_launch(void* const* d_in, const int* in_sizes, int n_in,
                              void* d_out, int out_size, void* d_ws, size_t ws_size,
                              hipStream_t stream) {
    const float* q = (const float*)d_in[0];
    const float* k = (const float*)d_in[1];
    const float* v = (const float*)d_in[2];
    float* o = (float*)d_out;

    ushort* kbf = (ushort*)d_ws;                       // 8 MB bf16 K [b][s][d]
    ushort* vtb = kbf + (size_t)32 * S_ * D_;          // 8 MB bf16 V^T [b][d][s]

    // K cvt: 32*2048*64 = 4,194,304 elems / 8 per thread = 2048 blocks
    prep_cvt<<<dim3(2048), dim3(256), 0, stream>>>(k, kbf);
    // V transpose+cvt: 32 batches * 32 key-tiles
    prep_vt<<<dim3(1024), dim3(256), 0, stream>>>(v, vtb);
    // flash: 32 batches * 32 q-tiles
    fattn<<<dim3(1024), dim3(256), 0, stream>>>(q, kbf, vtb, o);
}

// Round 4
// 174.847 us; speedup vs baseline: 1.4848x; 1.2533x over previous
//
#include <hip/hip_runtime.h>
#include <hip/hip_bf16.h>

#define S_ 2048
#define D_ 64
#define BM 64           // q rows per block (4 waves x 16)
#define BN 128          // key tile
#define KSTR 72         // Kt [key][d] row stride (ushort): 144B, 16B-aligned
#define VSTR 136        // Vt [d][key] row stride (ushort): 272B, 16B-aligned

typedef __attribute__((ext_vector_type(8))) short bf16x8;   // MFMA A/B frag
typedef __attribute__((ext_vector_type(4))) float f32x4;    // MFMA C/D frag

// half-up bf16 round: differs from RNE only on exact ties (prob 2^-16) — 2 ops
__device__ __forceinline__ unsigned int bfbits(float f) {
    union { float f; unsigned int i; } x; x.f = f;
    return x.i + 0x8000u;
}
__device__ __forceinline__ unsigned int pk2(float lo, float hi) {
    return (bfbits(hi) & 0xffff0000u) | (bfbits(lo) >> 16);
}

// ---- fused prep: K fp32->bf16 [b][s][d]; V fp32 [b][s][d] -> bf16 V^T [b][d][s] ----
// 1024 blocks: one (batch, 64-key tile) each.
__global__ __launch_bounds__(256) void prep(const float* __restrict__ k,
                                            const float* __restrict__ v,
                                            ushort* __restrict__ kbf,
                                            ushort* __restrict__ vtb) {
    __shared__ float Lf[64 * 68];
    const int batch = blockIdx.x >> 5;
    const int kt    = (blockIdx.x & 31) * 64;
    const int t     = threadIdx.x;

    // K convert (contiguous): 64 rows x 64 d = 512 8-elem chunks, 2/thread
    const float* kb = k + (size_t)batch * S_ * D_ + (size_t)kt * D_;
    ushort*      ko = kbf + (size_t)batch * S_ * D_ + (size_t)kt * D_;
#pragma unroll
    for (int p = 0; p < 2; ++p) {
        const int c = p * 256 + t;
        const float4 a = *(const float4*)(kb + c * 8);
        const float4 b = *(const float4*)(kb + c * 8 + 4);
        uint4 o;
        o.x = pk2(a.x, a.y); o.y = pk2(a.z, a.w);
        o.z = pk2(b.x, b.y); o.w = pk2(b.z, b.w);
        *(uint4*)(ko + c * 8) = o;
    }

    // V transpose via LDS
    const float* vb = v + (size_t)batch * S_ * D_ + (size_t)kt * D_;
#pragma unroll
    for (int p = 0; p < 4; ++p) {
        const int c   = p * 256 + t;
        const int key = c >> 4, dp = c & 15;
        *(float4*)(&Lf[key * 68 + dp * 4]) = *(const float4*)(vb + key * 64 + dp * 4);
    }
    __syncthreads();
    const int d = t >> 2, kg = t & 3;    // d row, 16-key group
    float x[16];
#pragma unroll
    for (int j = 0; j < 16; ++j) x[j] = Lf[(kg * 16 + j) * 68 + d];
    uint4 o0, o1;
    o0.x = pk2(x[0], x[1]);  o0.y = pk2(x[2], x[3]);
    o0.z = pk2(x[4], x[5]);  o0.w = pk2(x[6], x[7]);
    o1.x = pk2(x[8], x[9]);  o1.y = pk2(x[10], x[11]);
    o1.z = pk2(x[12], x[13]); o1.w = pk2(x[14], x[15]);
    ushort* ob = vtb + (size_t)batch * D_ * S_ + (size_t)d * S_ + kt + kg * 16;
    *(uint4*)(ob)     = o0;
    *(uint4*)(ob + 8) = o1;
}

// ---- flash attention, S^T formulation ----
// Q fp32 (scaled+cvt in-kernel); K bf16 [b][s][d]; V^T bf16 [b][d][s]; out fp32.
// QK: mfma(A=K,B=Q) -> S^T (lane: col=q=ln, rows=keys mt*16+quad*4+r).
// PV: O^T = mfma(A=V^T, B=P^T) with k-slot permutation sigma(f,quad,j) =
//     (f*2+(j>>2))*16 + quad*4 + (j&3)  -> B-frag is the lane's own sa regs.
__global__ __launch_bounds__(256, 4) void fattn(const float* __restrict__ q,
                                                const ushort* __restrict__ kbf,
                                                const ushort* __restrict__ vtb_g,
                                                float* __restrict__ out) {
    __shared__ ushort Kt[BN * KSTR];     // [key][d]
    __shared__ ushort Vt[D_ * VSTR];     // [d][key]

    const int tid  = threadIdx.x;
    const int wid  = tid >> 6;
    const int lane = tid & 63;
    const int ln   = lane & 15;
    const int quad = lane >> 4;

    const int batch = blockIdx.x >> 5;
    const int qtile = blockIdx.x & 31;

    const float*  qp  = q     + (size_t)batch * S_ * D_;
    const ushort* kp  = kbf   + (size_t)batch * S_ * D_;
    const ushort* vtb = vtb_g + (size_t)batch * D_ * S_;

    // ---- persistent Q B-frags, pre-scaled by log2(e)/sqrt(64) ----
    const float SC = 0.18033688011112042f;
    const int qr0 = qtile * BM + wid * 16;
    union { bf16x8 v; unsigned int u[4]; } uq0, uq1;
    {
        const float* qrow = qp + (size_t)(qr0 + ln) * D_ + quad * 8;
#pragma unroll
        for (int j = 0; j < 4; ++j) {
            uq0.u[j] = pk2(qrow[2 * j] * SC,      qrow[2 * j + 1] * SC);
            uq1.u[j] = pk2(qrow[32 + 2 * j] * SC, qrow[32 + 2 * j + 1] * SC);
        }
    }
    const bf16x8 qf0 = uq0.v, qf1 = uq1.v;

    const f32x4 zero4 = {0.f, 0.f, 0.f, 0.f};
    f32x4 O[4];                      // O^T accum: row d=mt*16+quad*4+r, col q=ln
#pragma unroll
    for (int mt = 0; mt < 4; ++mt) O[mt] = zero4;
    float m = -INFINITY, l = 0.f;

    for (int kt = 0; kt < S_; kt += BN) {
        __syncthreads();
        // ---- stage K [128][64] and V^T [64][128], pure uint4 copies ----
        {
            const ushort* ktile = kp + (size_t)kt * D_;
#pragma unroll
            for (int p = 0; p < 4; ++p) {
                const int c = p * 256 + tid;             // 1024 16B chunks
                *(uint4*)(&Kt[(c >> 3) * KSTR + (c & 7) * 8]) =
                    *(const uint4*)(ktile + c * 8);
            }
#pragma unroll
            for (int p = 0; p < 4; ++p) {
                const int c = p * 256 + tid;             // 1024 16B chunks
                const int d = c >> 4, part = c & 15;
                *(uint4*)(&Vt[d * VSTR + part * 8]) =
                    *(const uint4*)(vtb + (size_t)d * S_ + kt + part * 8);
            }
        }
        __syncthreads();

        // ---- S^T = K Q^T (scaled): 8 tiles of 16 keys ----
        f32x4 sa[8];
#pragma unroll
        for (int mt = 0; mt < 8; ++mt) {
            const ushort* kr = &Kt[(mt * 16 + ln) * KSTR + quad * 8];
            const bf16x8 k0 = *(const bf16x8*)(kr);
            const bf16x8 k1 = *(const bf16x8*)(kr + 32);
            f32x4 acc = __builtin_amdgcn_mfma_f32_16x16x32_bf16(k0, qf0, zero4, 0, 0, 0);
            sa[mt]    = __builtin_amdgcn_mfma_f32_16x16x32_bf16(k1, qf1, acc, 0, 0, 0);
        }

        // ---- online softmax: in-lane tree + 2 cross-quad shuffles ----
        f32x4 t0 = sa[0], t1 = sa[4];
#pragma unroll
        for (int mt = 1; mt < 4; ++mt) {
#pragma unroll
            for (int j = 0; j < 4; ++j) {
                t0[j] = fmaxf(t0[j], sa[mt][j]);
                t1[j] = fmaxf(t1[j], sa[mt + 4][j]);
            }
        }
        float tm = fmaxf(fmaxf(fmaxf(t0[0], t0[1]), fmaxf(t0[2], t0[3])),
                         fmaxf(fmaxf(t1[0], t1[1]), fmaxf(t1[2], t1[3])));
        tm = fmaxf(tm, __shfl_xor(tm, 16));
        tm = fmaxf(tm, __shfl_xor(tm, 32));
        const float mnew = fmaxf(m, tm);
        const float alpha = exp2f(m - mnew);
#pragma unroll
        for (int mt = 0; mt < 8; ++mt)
#pragma unroll
            for (int j = 0; j < 4; ++j) sa[mt][j] = exp2f(sa[mt][j] - mnew);
        f32x4 s0 = sa[0] + sa[1] + sa[2] + sa[3];
        f32x4 s1 = sa[4] + sa[5] + sa[6] + sa[7];
        s0 += s1;
        float rs = (s0[0] + s0[1]) + (s0[2] + s0[3]);
        rs += __shfl_xor(rs, 16);
        rs += __shfl_xor(rs, 32);
        l = l * alpha + rs;
        m = mnew;
#pragma unroll
        for (int mt = 0; mt < 4; ++mt) O[mt] *= alpha;

        // ---- O^T += V^T P^T (k-permuted; B-frag = own sa regs packed) ----
#pragma unroll
        for (int f = 0; f < 4; ++f) {
            union { bf16x8 v; unsigned int u[4]; } pf;
            pf.u[0] = pk2(sa[2 * f][0],     sa[2 * f][1]);
            pf.u[1] = pk2(sa[2 * f][2],     sa[2 * f][3]);
            pf.u[2] = pk2(sa[2 * f + 1][0], sa[2 * f + 1][1]);
            pf.u[3] = pk2(sa[2 * f + 1][2], sa[2 * f + 1][3]);
#pragma unroll
            for (int mt = 0; mt < 4; ++mt) {
                const ushort* vbase = &Vt[(mt * 16 + ln) * VSTR + quad * 4 + f * 32];
                union { bf16x8 v; uint2 p[2]; } vf;
                vf.p[0] = *(const uint2*)(vbase);        // keys f*32+quad*4+0..3
                vf.p[1] = *(const uint2*)(vbase + 16);   // keys f*32+16+quad*4+0..3
                O[mt] = __builtin_amdgcn_mfma_f32_16x16x32_bf16(vf.v, pf.v, O[mt], 0, 0, 0);
            }
        }
    }

    // ---- epilogue: out[q][d] = O^T[d][q] / l ; float4 per tile ----
    const float linv = 1.0f / l;
    float* op = out + (size_t)batch * S_ * D_ + (size_t)(qr0 + ln) * D_ + quad * 4;
#pragma unroll
    for (int mt = 0; mt < 4; ++mt) {
        float4 st;
        st.x = O[mt][0] * linv; st.y = O[mt][1] * linv;
        st.z = O[mt][2] * linv; st.w = O[mt][3] * linv;
        *(float4*)(op + mt * 16) = st;
    }
}

extern "C" void kernel_launch(void* const* d_in, const int* in_sizes, int n_in,
                              void* d_out, int out_size, void* d_ws, size_t ws_size,
                              hipStream_t stream) {
    const float* q = (const float*)d_in[0];
    const float* k = (const float*)d_in[1];
    const float* v = (const float*)d_in[2];
    float* o = (float*)d_out;

    ushort* kbf = (ushort*)d_ws;                       // 8 MB bf16 K [b][s][d]
    ushort* vtb = kbf + (size_t)32 * S_ * D_;          // 8 MB bf16 V^T [b][d][s]

    prep<<<dim3(1024), dim3(256), 0, stream>>>(k, v, kbf, vtb);
    fattn<<<dim3(1024), dim3(256), 0, stream>>>(q, kbf, vtb, o);
}